// Round 6
// baseline (20871.706 us; speedup 1.0000x reference)
//
#include <hip/hip_runtime.h>

// Problem constants
#define B_    32
#define T_    2048
#define F_    64
#define H_    256
#define OUT_  64
#define G3_   768           // 3*H
#define NWG   16            // worker WGs (cooperative)
#define WGT   512           // threads per WG (8 waves)
#define NITER (T_ + 1)      // pipelined: iter i computes h1[i] and h2[i-1]

// ws layout (bytes)
#define XN_BYTES   (B_ * T_ * F_ * 2)            // 8,388,608  fp16 LN(x), [T][B][F]
#define PACK_OFF   XN_BYTES
// pack: u32[layer][parity][w][bb][jl] = [2][2][16][32][16]  (stamp<<16 | fp16)
#define PACK_U32   (2 * 2 * 16 * 32 * 16)        // 32768 u32 = 128 KB

typedef _Float16 half8 __attribute__((ext_vector_type(8)));
typedef _Float16 half4 __attribute__((ext_vector_type(4)));
typedef float    f32x4 __attribute__((ext_vector_type(4)));
typedef unsigned u32x4 __attribute__((ext_vector_type(4)));

__device__ __forceinline__ float sigf(float x) {
    x = fminf(fmaxf(x, -30.f), 30.f);
    return 1.f / (1.f + __expf(-x));
}
__device__ __forceinline__ float tanhfast(float x) {
    x = fminf(fmaxf(x, -15.f), 15.f);
    float e = __expf(2.f * x);
    return (e - 1.f) / (e + 1.f);
}
__device__ __forceinline__ unsigned short f16b(float f) {
    union { _Float16 h; unsigned short u; } c; c.h = (_Float16)f; return c.u;
}
__device__ __forceinline__ unsigned* pline(unsigned* p, int layer, int par, int w, int bb) {
    return p + (((layer * 2 + par) * 16 + w) * 32 + bb) * 16;
}

// ---------------------------------------------------------------------------
// Init: out = bias broadcast; zero the pack region (stamps -> 0, never a live gen)
// ---------------------------------------------------------------------------
__global__ void init_kernel(float* __restrict__ out, const float* __restrict__ bd,
                            unsigned* __restrict__ pack) {
    int t = blockIdx.x * 256 + threadIdx.x;              // 16*256 = 4096 threads
    if (t < B_ * OUT_) out[t] = bd[t & (OUT_ - 1)];
    for (int p = t; p < PACK_U32; p += 4096) pack[p] = 0u;
}

// ---------------------------------------------------------------------------
// LayerNorm over F=64, fp16 output TRANSPOSED to [T][B][F].
// ---------------------------------------------------------------------------
__global__ __launch_bounds__(256) void ln_kernel(const float* __restrict__ x,
                                                 const float* __restrict__ gamma,
                                                 const float* __restrict__ beta,
                                                 _Float16* __restrict__ xn) {
    const int tid = threadIdx.x;
    const int r = tid >> 4, q = tid & 15;
    const size_t row = (size_t)blockIdx.x * 16 + r;      // = b*T + t
    const int b = (int)(row >> 11);
    const int t = (int)(row & 2047);
    const float4 v  = *(const float4*)(x + row * F_ + q * 4);
    const float4 g  = *(const float4*)(gamma + q * 4);
    const float4 be = *(const float4*)(beta + q * 4);
    float s = v.x + v.y + v.z + v.w;
    s += __shfl_xor(s, 1, 16); s += __shfl_xor(s, 2, 16);
    s += __shfl_xor(s, 4, 16); s += __shfl_xor(s, 8, 16);
    const float mu = s * (1.f / 64.f);
    const float dx = v.x - mu, dy = v.y - mu, dz = v.z - mu, dw = v.w - mu;
    float qq = dx * dx + dy * dy + dz * dz + dw * dw;
    qq += __shfl_xor(qq, 1, 16); qq += __shfl_xor(qq, 2, 16);
    qq += __shfl_xor(qq, 4, 16); qq += __shfl_xor(qq, 8, 16);
    const float rs = rsqrtf(qq * (1.f / 64.f) + 1e-3f);
    half4 o;
    o[0] = (_Float16)(dx * rs * g.x + be.x);
    o[1] = (_Float16)(dy * rs * g.y + be.y);
    o[2] = (_Float16)(dz * rs * g.z + be.z);
    o[3] = (_Float16)(dw * rs * g.w + be.w);
    *(half4*)(xn + ((size_t)t * B_ + b) * F_ + q * 4) = o;
}

// ---------------------------------------------------------------------------
// Persistent fused 2-layer GRU scan + final dense. 16 WGs x 512 (cooperative).
// NO barrier: every published u32 carries (gen<<16 | fp16). Producers publish
// fire-and-forget (relaxed agent stores, no drain, no flag). Consumers poll
// the stamped data directly: one IC round trip serves as barrier + payload.
// Skew is self-limited to 1 generation, so the 2-deep parity buffer is safe.
// ---------------------------------------------------------------------------
__global__ __launch_bounds__(WGT) void gru_main(
    const _Float16* __restrict__ xn,
    const float* __restrict__ k1, const float* __restrict__ rk1,
    const float* __restrict__ b1, const float* __restrict__ k2,
    const float* __restrict__ rk2, const float* __restrict__ b2,
    const float* __restrict__ wd, float* __restrict__ out,
    unsigned* __restrict__ pack) {
    const int w    = blockIdx.x;         // 0..15
    const int tid  = threadIdx.x;
    const int lane = tid & 63;
    const int wave = tid >> 6;           // 8 waves
    const int mt   = wave & 1;
    const int nt   = wave >> 1;          // 0..3
    const int ln   = lane & 15;
    const int quad = lane >> 4;

    // ---- B-operand fragments: lane holds B[k=quad*8+j][n=lane&15]
    const int  lc    = nt * 16 + ln;
    const bool valid = (lc < 48);
    const int  gate  = lc >> 4;
    const int  hidx  = lc & 15;
    const int  gcol  = valid ? (gate * H_ + w * 16 + hidx) : 0;

    half8 fk1[2], frk1[8], fk2[8], frk2[8];
#pragma unroll
    for (int ks = 0; ks < 2; ++ks) {
        half8 f;
#pragma unroll
        for (int j = 0; j < 8; ++j) {
            const int k = ks * 32 + quad * 8 + j;
            const float v = k1[k * G3_ + gcol];
            f[j] = valid ? (_Float16)v : (_Float16)0.f;
        }
        fk1[ks] = f;
    }
#pragma unroll
    for (int ks = 0; ks < 8; ++ks) {
        half8 f1, f2, f3;
#pragma unroll
        for (int j = 0; j < 8; ++j) {
            const int k = ks * 32 + quad * 8 + j;
            const float v1 = rk1[k * G3_ + gcol];
            const float v2 = k2 [k * G3_ + gcol];
            const float v3 = rk2[k * G3_ + gcol];
            f1[j] = valid ? (_Float16)v1 : (_Float16)0.f;
            f2[j] = valid ? (_Float16)v2 : (_Float16)0.f;
            f3[j] = valid ? (_Float16)v3 : (_Float16)0.f;
        }
        frk1[ks] = f1; fk2[ks] = f2; frk2[ks] = f3;
    }

    // ---- gate-phase mapping: thread -> (batch bb, local col jl)
    const int jl = tid & 15;
    const int bb = tid >> 4;             // 0..31
    const int gc = w * 16 + jl;
    const float b1xz = b1[gc],        b1xr = b1[H_ + gc],        b1xh = b1[2 * H_ + gc];
    const float b1hz = b1[G3_ + gc],  b1hr = b1[G3_ + H_ + gc],  b1hh = b1[G3_ + 2 * H_ + gc];
    const float b2xz = b2[gc],        b2xr = b2[H_ + gc],        b2xh = b2[2 * H_ + gc];
    const float b2hz = b2[G3_ + gc],  b2hr = b2[G3_ + H_ + gc],  b2hh = b2[G3_ + 2 * H_ + gc];

    float h1m = 0.f, h2m = 0.f;          // fp32 masters, register-resident

    __shared__ _Float16 h1s[32][264];    // 528B rows
    __shared__ _Float16 h2s[32][264];
    __shared__ float Cs[4][32][52];
    __shared__ float hs[32][16];

    const int m = mt * 16 + ln;          // batch row for A fragments

    // consumer staging mapping: thread t<512 -> (source WG w2, batch row bb2)
    const int w2  = tid & 15;
    const int bb2 = tid >> 4;

    for (int i = 0; i < NITER; ++i) {
        const int wb = i & 1;            // write parity (this gen)
        const int rp = (i + 1) & 1;      // read parity (gen i-1)

        // ---- xproj (independent of cross-WG data): issue first
        f32x4 c0 = {0.f, 0.f, 0.f, 0.f};
        if (i < T_) {
            half8 ax0 = *reinterpret_cast<const half8*>(xn + ((size_t)i * B_ + m) * F_ + quad * 8);
            half8 ax1 = *reinterpret_cast<const half8*>(xn + ((size_t)i * B_ + m) * F_ + 32 + quad * 8);
            c0 = __builtin_amdgcn_mfma_f32_16x16x32_f16(ax0, fk1[0], c0, 0, 0, 0);
            c0 = __builtin_amdgcn_mfma_f32_16x16x32_f16(ax1, fk1[1], c0, 0, 0, 0);
        }

        // ---- poll + stage: stamped data is its own barrier
        if (i >= 1) {
            unsigned* p1 = pline(pack, 0, rp, w2, bb2);
            unsigned* p2 = pline(pack, 1, rp, w2, bb2);
            const unsigned tgt = (unsigned)i;
            unsigned q1[16], q2[16];
            for (;;) {
#pragma unroll
                for (int k = 0; k < 16; ++k)
                    q1[k] = __hip_atomic_load(p1 + k, __ATOMIC_RELAXED, __HIP_MEMORY_SCOPE_AGENT);
#pragma unroll
                for (int k = 0; k < 16; ++k)
                    q2[k] = __hip_atomic_load(p2 + k, __ATOMIC_RELAXED, __HIP_MEMORY_SCOPE_AGENT);
                unsigned bad = 0;
#pragma unroll
                for (int k = 0; k < 16; ++k) bad |= (q1[k] >> 16) ^ tgt;
#pragma unroll
                for (int k = 0; k < 16; ++k) bad |= (q2[k] >> 16) ^ tgt;
                if (bad == 0) break;
                __builtin_amdgcn_s_sleep(2);
            }
            u32x4 o1a, o1b, o2a, o2b;
#pragma unroll
            for (int k = 0; k < 4; ++k) {
                o1a[k] = (q1[2 * k]     & 0xffffu) | (q1[2 * k + 1] << 16);
                o1b[k] = (q1[2 * k + 8] & 0xffffu) | (q1[2 * k + 9] << 16);
                o2a[k] = (q2[2 * k]     & 0xffffu) | (q2[2 * k + 1] << 16);
                o2b[k] = (q2[2 * k + 8] & 0xffffu) | (q2[2 * k + 9] << 16);
            }
            *(u32x4*)(&h1s[bb2][w2 * 16])     = o1a;
            *(u32x4*)(&h1s[bb2][w2 * 16 + 8]) = o1b;
            *(u32x4*)(&h2s[bb2][w2 * 16])     = o2a;
            *(u32x4*)(&h2s[bb2][w2 * 16 + 8]) = o2b;
        }
        __syncthreads();

        // ---- recurrent MFMAs
        f32x4 c1 = {0.f, 0.f, 0.f, 0.f};
        f32x4 c2 = c1, c3 = c1;
        if (i >= 1) {
#pragma unroll
            for (int ks = 0; ks < 8; ++ks) {   // h1[i-1] -> rk1 (inner1) and k2 (x2)
                half8 a1 = *reinterpret_cast<const half8*>(&h1s[m][ks * 32 + quad * 8]);
                c1 = __builtin_amdgcn_mfma_f32_16x16x32_f16(a1, frk1[ks], c1, 0, 0, 0);
                c2 = __builtin_amdgcn_mfma_f32_16x16x32_f16(a1, fk2[ks],  c2, 0, 0, 0);
            }
#pragma unroll
            for (int ks = 0; ks < 8; ++ks) {   // h2[i-2] -> rk2 (inner2)
                half8 a2 = *reinterpret_cast<const half8*>(&h2s[m][ks * 32 + quad * 8]);
                c3 = __builtin_amdgcn_mfma_f32_16x16x32_f16(a2, frk2[ks], c3, 0, 0, 0);
            }
        }

        // C/D layout: col = lane&15, row = quad*4 + reg
        if (valid) {
            const int r0 = mt * 16 + quad * 4;
#pragma unroll
            for (int rr = 0; rr < 4; ++rr) {
                Cs[0][r0 + rr][lc] = c0[rr];
                Cs[1][r0 + rr][lc] = c1[rr];
                Cs[2][r0 + rr][lc] = c2[rr];
                Cs[3][r0 + rr][lc] = c3[rr];
            }
        }
        __syncthreads();

        if (i < T_) {   // layer-1 gate combine for step i
            const float xz = Cs[0][bb][jl]      + b1xz;
            const float xr = Cs[0][bb][16 + jl] + b1xr;
            const float xh = Cs[0][bb][32 + jl] + b1xh;
            const float rz = Cs[1][bb][jl]      + b1hz;
            const float rr = Cs[1][bb][16 + jl] + b1hr;
            const float rh = Cs[1][bb][32 + jl] + b1hh;
            const float z  = sigf(xz + rz);
            const float r  = sigf(xr + rr);
            const float hh = tanhfast(xh + r * rh);
            h1m = z * h1m + (1.f - z) * hh;
        }
        if (i >= 1) {   // layer-2 gate combine for step i-1
            const float xz = Cs[2][bb][jl]      + b2xz;
            const float xr = Cs[2][bb][16 + jl] + b2xr;
            const float xh = Cs[2][bb][32 + jl] + b2xh;
            const float rz = Cs[3][bb][jl]      + b2hz;
            const float rr = Cs[3][bb][16 + jl] + b2hr;
            const float rh = Cs[3][bb][32 + jl] + b2hh;
            const float z  = sigf(xz + rz);
            const float r  = sigf(xr + rr);
            const float hh = tanhfast(xh + r * rh);
            h2m = z * h2m + (1.f - z) * hh;
        }

        // ---- publish: fire-and-forget stamped stores (no drain, no flag)
        if (i < T_) {
            const unsigned s = ((unsigned)(i + 1)) << 16;
            __hip_atomic_store(pline(pack, 0, wb, w, bb) + jl, s | f16b(h1m),
                               __ATOMIC_RELAXED, __HIP_MEMORY_SCOPE_AGENT);
            __hip_atomic_store(pline(pack, 1, wb, w, bb) + jl, s | f16b(h2m),
                               __ATOMIC_RELAXED, __HIP_MEMORY_SCOPE_AGENT);
        }
        __syncthreads();   // protect Cs / h1s / h2s for next iteration
    }

    // ---- final dense: out[b][o] += sum_j h2[b][16w+j] * wd[16w+j][o]
    hs[bb][jl] = h2m;
    __syncthreads();
    const int o  = tid & 63;
    const int bq = tid >> 6;             // 0..7
    for (int pass = 0; pass < 4; ++pass) {
        const int b = pass * 8 + bq;
        float acc = 0.f;
#pragma unroll
        for (int j = 0; j < 16; ++j) acc += hs[b][j] * wd[(w * 16 + j) * OUT_ + o];
        atomicAdd(&out[b * OUT_ + o], acc);
    }
}

// ---------------------------------------------------------------------------
extern "C" void kernel_launch(void* const* d_in, const int* in_sizes, int n_in,
                              void* d_out, int out_size, void* d_ws, size_t ws_size,
                              hipStream_t stream) {
    const float* x     = (const float*)d_in[0];
    const float* gamma = (const float*)d_in[1];
    const float* beta  = (const float*)d_in[2];
    const float* k1    = (const float*)d_in[3];
    const float* rk1   = (const float*)d_in[4];
    const float* b1    = (const float*)d_in[5];
    const float* k2    = (const float*)d_in[6];
    const float* rk2   = (const float*)d_in[7];
    const float* b2    = (const float*)d_in[8];
    const float* wd    = (const float*)d_in[9];
    const float* bd    = (const float*)d_in[10];
    float* out = (float*)d_out;

    char* ws = (char*)d_ws;
    _Float16* xn   = (_Float16*)ws;
    unsigned* pack = (unsigned*)(ws + PACK_OFF);

    hipLaunchKernelGGL(init_kernel, dim3(16), dim3(256), 0, stream, out, bd, pack);
    hipLaunchKernelGGL(ln_kernel, dim3(B_ * T_ / 16), dim3(256), 0, stream, x, gamma, beta, xn);

    void* args[] = {(void*)&xn, (void*)&k1, (void*)&rk1, (void*)&b1, (void*)&k2,
                    (void*)&rk2, (void*)&b2, (void*)&wd, (void*)&out, (void*)&pack};
    hipLaunchCooperativeKernel((void*)gru_main, dim3(NWG), dim3(WGT), args, 0, stream);
}

// Round 7
// 10527.115 us; speedup vs baseline: 1.9827x; 1.9827x over previous
//
#include <hip/hip_runtime.h>

// Problem constants
#define B_    32
#define T_    2048
#define F_    64
#define H_    256
#define OUT_  64
#define G3_   768           // 3*H
#define NWG   16            // worker WGs (cooperative)
#define WGT   512           // threads per WG (8 waves)
#define NITER (T_ + 2)      // iter i: h1[i] (layer1), h2[i-2] (layer2, lag 2)

// ws layout (bytes)
#define XN_BYTES   (B_ * T_ * F_ * 2)            // 8,388,608  fp16 LN(x), [T][B][F]
#define PACK_OFF   XN_BYTES
#define PACK_ELEMS (B_ * H_)                     // 8192 fp16 per buffer
#define PACK_BYTES (4 * PACK_ELEMS * 2)          // h1[2 parity] + h2[2 parity]
#define FLAG_OFF   (PACK_OFF + PACK_BYTES)       // 32 lines x 64B = 2 KB

typedef _Float16 half8 __attribute__((ext_vector_type(8)));
typedef _Float16 half4 __attribute__((ext_vector_type(4)));
typedef float    f32x4 __attribute__((ext_vector_type(4)));
typedef unsigned u32x4 __attribute__((ext_vector_type(4)));
typedef unsigned long long u64;

__device__ __forceinline__ float sigf(float x) {
    x = fminf(fmaxf(x, -30.f), 30.f);
    return 1.f / (1.f + __expf(-x));
}
__device__ __forceinline__ float tanhfast(float x) {
    x = fminf(fmaxf(x, -15.f), 15.f);
    float e = __expf(2.f * x);
    return (e - 1.f) / (e + 1.f);
}
__device__ __forceinline__ unsigned short f16b(float f) {
    union { _Float16 h; unsigned short u; } c; c.h = (_Float16)f; return c.u;
}
// Gather 4 neighboring lanes' fp16 (jl, jl^1, jl^2, jl^3) into one u64 (LE by jl)
__device__ __forceinline__ u64 gather4(unsigned short u, int jl) {
    unsigned int p = (unsigned int)__shfl_xor((int)(unsigned int)u, 1);
    unsigned int lo32 = (jl & 1) ? ((p & 0xffffu) | ((unsigned int)u << 16))
                                 : ((unsigned int)u | (p << 16));
    unsigned int q = (unsigned int)__shfl_xor((int)lo32, 2);
    return (jl & 2) ? (((u64)lo32 << 32) | q)
                    : ((u64)lo32 | ((u64)q << 32));
}

// ---------------------------------------------------------------------------
// Init: zero flags + h-pack buffers, out = bias broadcast
// ---------------------------------------------------------------------------
__global__ void init_kernel(float* __restrict__ out, const float* __restrict__ bd,
                            _Float16* __restrict__ packs, unsigned int* __restrict__ flg) {
    int t = blockIdx.x * 256 + threadIdx.x;              // 16*256 = 4096 threads
    if (t < B_ * OUT_) out[t] = bd[t & (OUT_ - 1)];
    if (t < 512) flg[t] = 0u;                            // 32 flag lines (2 KB)
    for (int p = t; p < 4 * PACK_ELEMS; p += 4096) packs[p] = (_Float16)0.f;
}

// ---------------------------------------------------------------------------
// LayerNorm over F=64, fp16 output TRANSPOSED to [T][B][F].
// ---------------------------------------------------------------------------
__global__ __launch_bounds__(256) void ln_kernel(const float* __restrict__ x,
                                                 const float* __restrict__ gamma,
                                                 const float* __restrict__ beta,
                                                 _Float16* __restrict__ xn) {
    const int tid = threadIdx.x;
    const int r = tid >> 4, q = tid & 15;
    const size_t row = (size_t)blockIdx.x * 16 + r;      // = b*T + t
    const int b = (int)(row >> 11);
    const int t = (int)(row & 2047);
    const float4 v  = *(const float4*)(x + row * F_ + q * 4);
    const float4 g  = *(const float4*)(gamma + q * 4);
    const float4 be = *(const float4*)(beta + q * 4);
    float s = v.x + v.y + v.z + v.w;
    s += __shfl_xor(s, 1, 16); s += __shfl_xor(s, 2, 16);
    s += __shfl_xor(s, 4, 16); s += __shfl_xor(s, 8, 16);
    const float mu = s * (1.f / 64.f);
    const float dx = v.x - mu, dy = v.y - mu, dz = v.z - mu, dw = v.w - mu;
    float qq = dx * dx + dy * dy + dz * dz + dw * dw;
    qq += __shfl_xor(qq, 1, 16); qq += __shfl_xor(qq, 2, 16);
    qq += __shfl_xor(qq, 4, 16); qq += __shfl_xor(qq, 8, 16);
    const float rs = rsqrtf(qq * (1.f / 64.f) + 1e-3f);
    half4 o;
    o[0] = (_Float16)(dx * rs * g.x + be.x);
    o[1] = (_Float16)(dy * rs * g.y + be.y);
    o[2] = (_Float16)(dz * rs * g.z + be.z);
    o[3] = (_Float16)(dw * rs * g.w + be.w);
    *(half4*)(xn + ((size_t)t * B_ + b) * F_ + q * 4) = o;
}

// ---------------------------------------------------------------------------
// Persistent fused 2-layer GRU scan + final dense. 16 WGs x 512 (cooperative).
// Iter i: layer1 computes h1[i]; layer2 (lag 2) computes h2[i-2] using
// register-carried x2 = h1[i-2]@k2 (c2p, from iter i-1) and staged h2[i-3].
// h1 is published + flagged MID-iteration; layer-2 runs in its shadow.
// Per-WG flags: h1flag[w]=i+1 after publishing h1[i]; h2flag[w]=i-1 after
// publishing h2[i-2]. h1flag advances even for i>=T (data-less) so the
// h1-chain ordering covers tail parity reuse.
// ---------------------------------------------------------------------------
__global__ __launch_bounds__(WGT) void gru_main(
    const _Float16* __restrict__ xn,
    const float* __restrict__ k1, const float* __restrict__ rk1,
    const float* __restrict__ b1, const float* __restrict__ k2,
    const float* __restrict__ rk2, const float* __restrict__ b2,
    const float* __restrict__ wd, float* __restrict__ out,
    _Float16* __restrict__ packs, unsigned int* __restrict__ flags) {
    const int w    = blockIdx.x;         // 0..15
    const int tid  = threadIdx.x;
    const int lane = tid & 63;
    const int wave = tid >> 6;           // 8 waves
    const int mt   = wave & 1;
    const int nt   = wave >> 1;          // 0..3
    const int ln   = lane & 15;
    const int quad = lane >> 4;

    // ---- B-operand fragments: lane holds B[k=quad*8+j][n=lane&15]
    const int  lc    = nt * 16 + ln;
    const bool valid = (lc < 48);
    const int  gate  = lc >> 4;
    const int  hidx  = lc & 15;
    const int  gcol  = valid ? (gate * H_ + w * 16 + hidx) : 0;

    half8 fk1[2], frk1[8], fk2[8], frk2[8];
#pragma unroll
    for (int ks = 0; ks < 2; ++ks) {
        half8 f;
#pragma unroll
        for (int j = 0; j < 8; ++j) {
            const int k = ks * 32 + quad * 8 + j;
            const float v = k1[k * G3_ + gcol];
            f[j] = valid ? (_Float16)v : (_Float16)0.f;
        }
        fk1[ks] = f;
    }
#pragma unroll
    for (int ks = 0; ks < 8; ++ks) {
        half8 f1, f2, f3;
#pragma unroll
        for (int j = 0; j < 8; ++j) {
            const int k = ks * 32 + quad * 8 + j;
            const float v1 = rk1[k * G3_ + gcol];
            const float v2 = k2 [k * G3_ + gcol];
            const float v3 = rk2[k * G3_ + gcol];
            f1[j] = valid ? (_Float16)v1 : (_Float16)0.f;
            f2[j] = valid ? (_Float16)v2 : (_Float16)0.f;
            f3[j] = valid ? (_Float16)v3 : (_Float16)0.f;
        }
        frk1[ks] = f1; fk2[ks] = f2; frk2[ks] = f3;
    }

    // ---- gate-phase mapping: thread -> (batch bb, local col jl)
    const int jl = tid & 15;
    const int bb = tid >> 4;             // 0..31
    const int gc = w * 16 + jl;
    const float b1xz = b1[gc],        b1xr = b1[H_ + gc],        b1xh = b1[2 * H_ + gc];
    const float b1hz = b1[G3_ + gc],  b1hr = b1[G3_ + H_ + gc],  b1hh = b1[G3_ + 2 * H_ + gc];
    const float b2xz = b2[gc],        b2xr = b2[H_ + gc],        b2xh = b2[2 * H_ + gc];
    const float b2hz = b2[G3_ + gc],  b2hr = b2[G3_ + H_ + gc],  b2hh = b2[G3_ + 2 * H_ + gc];

    float h1m = 0.f, h2m = 0.f;          // fp32 masters
    f32x4 c2p = {0.f, 0.f, 0.f, 0.f};    // register-carried x2 = h1[i-2]@k2

    __shared__ _Float16 h1s[32][264];    // 528B rows
    __shared__ _Float16 h2s[32][264];
    __shared__ float Cs[4][32][52];
    __shared__ float hs[32][16];

    const int m = mt * 16 + ln;          // batch row for A fragments

    // staging mapping: thread -> (buffer sel, batch row sb, 64B segment)
    const int sel = tid >> 8;            // 0: h1, 1: h2
    const int sb  = (tid & 255) >> 3;
    const int seg = tid & 7;

    for (int i = 0; i < NITER; ++i) {
        const int rp = (i + 1) & 1;      // read parity (gen i-1)
        const int wb = i & 1;            // write parity
        const _Float16* h1r = packs + rp * PACK_ELEMS;
        const _Float16* h2r = packs + 2 * PACK_ELEMS + rp * PACK_ELEMS;
        _Float16* h1w = packs + wb * PACK_ELEMS;
        _Float16* h2w = packs + 2 * PACK_ELEMS + wb * PACK_ELEMS;

        // ---- xproj (independent): issue before polling
        f32x4 c0 = {0.f, 0.f, 0.f, 0.f};
        if (i < T_) {
            half8 ax0 = *reinterpret_cast<const half8*>(xn + ((size_t)i * B_ + m) * F_ + quad * 8);
            half8 ax1 = *reinterpret_cast<const half8*>(xn + ((size_t)i * B_ + m) * F_ + 32 + quad * 8);
            c0 = __builtin_amdgcn_mfma_f32_16x16x32_f16(ax0, fk1[0], c0, 0, 0, 0);
            c0 = __builtin_amdgcn_mfma_f32_16x16x32_f16(ax1, fk1[1], c0, 0, 0, 0);
        }

        // ---- narrow poll: h1flag >= i (16 lines), h2flag >= i-2 (16 lines)
        if (tid < 32) {
            const int isH2 = tid >> 4;
            const int src  = tid & 15;
            const unsigned tgt = isH2 ? (unsigned)(i >= 3 ? i - 2 : 0) : (unsigned)i;
            const unsigned* fp = flags + (isH2 * NWG + src) * 16;
            while (__hip_atomic_load(fp, __ATOMIC_RELAXED, __HIP_MEMORY_SCOPE_AGENT) < tgt)
                __builtin_amdgcn_s_sleep(1);
        }
        __syncthreads();

        // ---- stage packs -> LDS (agent loads, b128 LDS writes)
        {
            const _Float16* sp = (sel ? h2r : h1r) + sb * H_ + seg * 32;
            u64 q[8];
#pragma unroll
            for (int k = 0; k < 8; ++k)
                q[k] = __hip_atomic_load((const u64*)sp + k, __ATOMIC_RELAXED,
                                         __HIP_MEMORY_SCOPE_AGENT);
            _Float16* dp = sel ? &h2s[sb][seg * 32] : &h1s[sb][seg * 32];
#pragma unroll
            for (int k = 0; k < 4; ++k) {
                union { u64 q2[2]; u32x4 v; } u;
                u.q2[0] = q[2 * k]; u.q2[1] = q[2 * k + 1];
                *(u32x4*)(dp + k * 8) = u.v;
            }
        }
        __syncthreads();

        // ---- MFMAs: c1 (h1 recurrence, critical), c2_cur (x2 for next iter),
        //             c3 (h2 recurrence, shadow)
        f32x4 c1 = {0.f, 0.f, 0.f, 0.f};
        f32x4 c2c = c1, c3 = c1;
        if (i < T_) {
#pragma unroll
            for (int ks = 0; ks < 8; ++ks) {
                half8 a1 = *reinterpret_cast<const half8*>(&h1s[m][ks * 32 + quad * 8]);
                c1 = __builtin_amdgcn_mfma_f32_16x16x32_f16(a1, frk1[ks], c1, 0, 0, 0);
            }
        }
        if (i <= T_) {
#pragma unroll
            for (int ks = 0; ks < 8; ++ks) {
                half8 a1 = *reinterpret_cast<const half8*>(&h1s[m][ks * 32 + quad * 8]);
                c2c = __builtin_amdgcn_mfma_f32_16x16x32_f16(a1, fk2[ks], c2c, 0, 0, 0);
            }
        }
        if (i >= 2) {
#pragma unroll
            for (int ks = 0; ks < 8; ++ks) {
                half8 a2 = *reinterpret_cast<const half8*>(&h2s[m][ks * 32 + quad * 8]);
                c3 = __builtin_amdgcn_mfma_f32_16x16x32_f16(a2, frk2[ks], c3, 0, 0, 0);
            }
        }

        // C/D layout: col = lane&15, row = quad*4 + reg
        if (valid) {
            const int r0 = mt * 16 + quad * 4;
#pragma unroll
            for (int rr = 0; rr < 4; ++rr) {
                Cs[0][r0 + rr][lc] = c0[rr];
                Cs[1][r0 + rr][lc] = c1[rr];
                Cs[2][r0 + rr][lc] = c2p[rr];   // x2 = h1[i-2]@k2, carried
                Cs[3][r0 + rr][lc] = c3[rr];
            }
        }
        c2p = c2c;
        __syncthreads();

        // ---- layer-1 gates + EARLY publish of h1[i]
        if (i < T_) {
            const float xz = Cs[0][bb][jl]      + b1xz;
            const float xr = Cs[0][bb][16 + jl] + b1xr;
            const float xh = Cs[0][bb][32 + jl] + b1xh;
            const float rz = Cs[1][bb][jl]      + b1hz;
            const float rr = Cs[1][bb][16 + jl] + b1hr;
            const float rh = Cs[1][bb][32 + jl] + b1hh;
            const float z  = sigf(xz + rz);
            const float r  = sigf(xr + rr);
            const float hh = tanhfast(xh + r * rh);
            h1m = z * h1m + (1.f - z) * hh;
            const u64 v1 = gather4(f16b(h1m), jl);
            if ((jl & 3) == 0)
                __hip_atomic_store((u64*)(h1w + bb * H_ + w * 16 + jl), v1,
                                   __ATOMIC_RELAXED, __HIP_MEMORY_SCOPE_AGENT);
            asm volatile("s_waitcnt vmcnt(0)" ::: "memory");
        }
        __syncthreads();                 // all waves' h1 stores drained (or no-op tail)
        if (tid == 0)
            __hip_atomic_store(&flags[w * 16], (unsigned)(i + 1),
                               __ATOMIC_RELAXED, __HIP_MEMORY_SCOPE_AGENT);

        // ---- layer-2 gates (step i-2) in the shadow of the h1 chain
        if (i >= 2) {
            const float xz = Cs[2][bb][jl]      + b2xz;
            const float xr = Cs[2][bb][16 + jl] + b2xr;
            const float xh = Cs[2][bb][32 + jl] + b2xh;
            const float rz = Cs[3][bb][jl]      + b2hz;
            const float rr = Cs[3][bb][16 + jl] + b2hr;
            const float rh = Cs[3][bb][32 + jl] + b2hh;
            const float z  = sigf(xz + rz);
            const float r  = sigf(xr + rr);
            const float hh = tanhfast(xh + r * rh);
            h2m = z * h2m + (1.f - z) * hh;
            const u64 v2 = gather4(f16b(h2m), jl);
            if ((jl & 3) == 0)
                __hip_atomic_store((u64*)(h2w + bb * H_ + w * 16 + jl), v2,
                                   __ATOMIC_RELAXED, __HIP_MEMORY_SCOPE_AGENT);
            asm volatile("s_waitcnt vmcnt(0)" ::: "memory");
            __syncthreads();             // all waves' h2 stores drained
            if (tid == 0)
                __hip_atomic_store(&flags[(NWG + w) * 16], (unsigned)(i - 1),
                                   __ATOMIC_RELAXED, __HIP_MEMORY_SCOPE_AGENT);
        } else {
            __syncthreads();             // keep barrier count uniform per iter
        }
    }

    // ---- final dense: out[b][o] += sum_j h2[b][16w+j] * wd[16w+j][o]
    hs[bb][jl] = h2m;                    // h2m = h2[T-1]
    __syncthreads();
    const int o  = tid & 63;
    const int bq = tid >> 6;             // 0..7
    for (int pass = 0; pass < 4; ++pass) {
        const int b = pass * 8 + bq;
        float acc = 0.f;
#pragma unroll
        for (int j = 0; j < 16; ++j) acc += hs[b][j] * wd[(w * 16 + j) * OUT_ + o];
        atomicAdd(&out[b * OUT_ + o], acc);
    }
}

// ---------------------------------------------------------------------------
extern "C" void kernel_launch(void* const* d_in, const int* in_sizes, int n_in,
                              void* d_out, int out_size, void* d_ws, size_t ws_size,
                              hipStream_t stream) {
    const float* x     = (const float*)d_in[0];
    const float* gamma = (const float*)d_in[1];
    const float* beta  = (const float*)d_in[2];
    const float* k1    = (const float*)d_in[3];
    const float* rk1   = (const float*)d_in[4];
    const float* b1    = (const float*)d_in[5];
    const float* k2    = (const float*)d_in[6];
    const float* rk2   = (const float*)d_in[7];
    const float* b2    = (const float*)d_in[8];
    const float* wd    = (const float*)d_in[9];
    const float* bd    = (const float*)d_in[10];
    float* out = (float*)d_out;

    char* ws = (char*)d_ws;
    _Float16*     xn    = (_Float16*)ws;
    _Float16*     packs = (_Float16*)(ws + PACK_OFF);
    unsigned int* flags = (unsigned int*)(ws + FLAG_OFF);

    hipLaunchKernelGGL(init_kernel, dim3(16), dim3(256), 0, stream, out, bd, packs, flags);
    hipLaunchKernelGGL(ln_kernel, dim3(B_ * T_ / 16), dim3(256), 0, stream, x, gamma, beta, xn);

    void* args[] = {(void*)&xn, (void*)&k1, (void*)&rk1, (void*)&b1, (void*)&k2,
                    (void*)&rk2, (void*)&b2, (void*)&wd, (void*)&out, (void*)&packs,
                    (void*)&flags};
    hipLaunchCooperativeKernel((void*)gru_main, dim3(NWG), dim3(WGT), args, 0, stream);
}

// Round 8
// 7575.825 us; speedup vs baseline: 2.7550x; 1.3896x over previous
//
#include <hip/hip_runtime.h>

// Problem constants
#define B_    32
#define T_    2048
#define F_    64
#define H_    256
#define OUT_  64
#define G3_   768           // 3*H
#define NWG1  16            // layer-1 pipeline WGs
#define NWG2  16            // layer-2 pipeline WGs
#define TOTAL_WG (NWG1 + NWG2)
#define WGT   512           // threads per WG (8 waves)

// ws layout (bytes)
#define XN_BYTES   (B_ * T_ * F_ * 2)            // 8,388,608  fp16 LN(x), [T][B][F]
#define PACK_ELEMS (B_ * H_)                     // 8192 fp16 per buffer
#define P1_OFF     XN_BYTES                      // h1: 4 parities (64 KB)
#define P2_OFF     (P1_OFF + 4 * PACK_ELEMS * 2) // h2: 2 parities (32 KB)
#define FLAG_OFF   (P2_OFF + 2 * PACK_ELEMS * 2) // 32 lines x 64B
// flags: lines 0..15 = h1flag[w], lines 16..31 = h2flag[w]

typedef _Float16 half8 __attribute__((ext_vector_type(8)));
typedef _Float16 half4 __attribute__((ext_vector_type(4)));
typedef float    f32x4 __attribute__((ext_vector_type(4)));
typedef unsigned u32x4 __attribute__((ext_vector_type(4)));
typedef unsigned long long u64;

#define LD_A(p)    __hip_atomic_load((p),  __ATOMIC_RELAXED, __HIP_MEMORY_SCOPE_AGENT)
#define ST_A(p, v) __hip_atomic_store((p), (v), __ATOMIC_RELAXED, __HIP_MEMORY_SCOPE_AGENT)

__device__ __forceinline__ float sigf(float x) {
    x = fminf(fmaxf(x, -30.f), 30.f);
    return 1.f / (1.f + __expf(-x));
}
__device__ __forceinline__ float tanhfast(float x) {
    x = fminf(fmaxf(x, -15.f), 15.f);
    float e = __expf(2.f * x);
    return (e - 1.f) / (e + 1.f);
}
__device__ __forceinline__ unsigned short f16b(float f) {
    union { _Float16 h; unsigned short u; } c; c.h = (_Float16)f; return c.u;
}
// Gather 4 neighboring lanes' fp16 (jl, jl^1, jl^2, jl^3) into one u64 (LE by jl)
__device__ __forceinline__ u64 gather4(unsigned short u, int jl) {
    unsigned int p = (unsigned int)__shfl_xor((int)(unsigned int)u, 1);
    unsigned int lo32 = (jl & 1) ? ((p & 0xffffu) | ((unsigned int)u << 16))
                                 : ((unsigned int)u | (p << 16));
    unsigned int q = (unsigned int)__shfl_xor((int)lo32, 2);
    return (jl & 2) ? (((u64)lo32 << 32) | q)
                    : ((u64)lo32 | ((u64)q << 32));
}

// ---------------------------------------------------------------------------
// Init: zero flags + all pack parities, out = bias broadcast
// ---------------------------------------------------------------------------
__global__ void init_kernel(float* __restrict__ out, const float* __restrict__ bd,
                            _Float16* __restrict__ p1, unsigned int* __restrict__ flg) {
    int t = blockIdx.x * 256 + threadIdx.x;              // 16*256 = 4096 threads
    if (t < B_ * OUT_) out[t] = bd[t & (OUT_ - 1)];
    if (t < 512) flg[t] = 0u;
    for (int p = t; p < 6 * PACK_ELEMS; p += 4096) p1[p] = (_Float16)0.f;  // h1x4 + h2x2
}

// ---------------------------------------------------------------------------
// LayerNorm over F=64, fp16 output TRANSPOSED to [T][B][F].
// ---------------------------------------------------------------------------
__global__ __launch_bounds__(256) void ln_kernel(const float* __restrict__ x,
                                                 const float* __restrict__ gamma,
                                                 const float* __restrict__ beta,
                                                 _Float16* __restrict__ xn) {
    const int tid = threadIdx.x;
    const int r = tid >> 4, q = tid & 15;
    const size_t row = (size_t)blockIdx.x * 16 + r;      // = b*T + t
    const int b = (int)(row >> 11);
    const int t = (int)(row & 2047);
    const float4 v  = *(const float4*)(x + row * F_ + q * 4);
    const float4 g  = *(const float4*)(gamma + q * 4);
    const float4 be = *(const float4*)(beta + q * 4);
    float s = v.x + v.y + v.z + v.w;
    s += __shfl_xor(s, 1, 16); s += __shfl_xor(s, 2, 16);
    s += __shfl_xor(s, 4, 16); s += __shfl_xor(s, 8, 16);
    const float mu = s * (1.f / 64.f);
    const float dx = v.x - mu, dy = v.y - mu, dz = v.z - mu, dw = v.w - mu;
    float qq = dx * dx + dy * dy + dz * dz + dw * dw;
    qq += __shfl_xor(qq, 1, 16); qq += __shfl_xor(qq, 2, 16);
    qq += __shfl_xor(qq, 4, 16); qq += __shfl_xor(qq, 8, 16);
    const float rs = rsqrtf(qq * (1.f / 64.f) + 1e-3f);
    half4 o;
    o[0] = (_Float16)(dx * rs * g.x + be.x);
    o[1] = (_Float16)(dy * rs * g.y + be.y);
    o[2] = (_Float16)(dz * rs * g.z + be.z);
    o[3] = (_Float16)(dw * rs * g.w + be.w);
    *(half4*)(xn + ((size_t)t * B_ + b) * F_ + q * 4) = o;
}

// ---------------------------------------------------------------------------
// Dual-pipeline persistent GRU. 32 WGs x 512 (cooperative).
// WGs 0..15  (L1): h1 recurrence. Step i: poll h1flags>=i (+ h2flag>=i-3
//   back-pressure), stage h1[i-1], inner1 MFMA + prefetched xproj, gates,
//   publish h1[i] (parity i&3, depth 4), flag.
// WGs 16..31 (L2): h2 recurrence, lag ~1 behind L1. Step t: poll h1flag>=t+1
//   & h2flag>=t, stage h1[t] + h2[t-1], x2(=h1[t]@k2)+inner2 MFMA, gates,
//   publish h2[t] (parity t&1), flag. Epilogue dense from h2[T-1].
// The two chains run on disjoint CUs concurrently: step = max, not sum.
// ---------------------------------------------------------------------------
__global__ __launch_bounds__(WGT) void gru_main(
    const _Float16* __restrict__ xn,
    const float* __restrict__ k1, const float* __restrict__ rk1,
    const float* __restrict__ b1, const float* __restrict__ k2,
    const float* __restrict__ rk2, const float* __restrict__ b2,
    const float* __restrict__ wd, float* __restrict__ out,
    _Float16* __restrict__ p1, _Float16* __restrict__ p2,
    unsigned int* __restrict__ flags) {
    const int tid  = threadIdx.x;
    const int lane = tid & 63;
    const int wave = tid >> 6;           // 8 waves
    const int mt   = wave & 1;
    const int nt   = wave >> 1;          // 0..3
    const int ln   = lane & 15;
    const int quad = lane >> 4;

    __shared__ _Float16 h1s[32][264];    // 528B rows
    __shared__ _Float16 h2s[32][264];
    __shared__ float Cs[2][32][52];
    __shared__ float hs[32][16];

    const int  lc    = nt * 16 + ln;
    const bool valid = (lc < 48);
    const int  gate  = lc >> 4;
    const int  hidx  = lc & 15;
    const int  jl    = tid & 15;
    const int  bb    = tid >> 4;         // 0..31
    const int  m     = mt * 16 + ln;     // batch row for A fragments

    if (blockIdx.x < NWG1) {
        // ================= L1 pipeline =================
        const int w    = blockIdx.x;
        const int gcol = valid ? (gate * H_ + w * 16 + hidx) : 0;
        half8 fk1[2], frk1[8];
#pragma unroll
        for (int ks = 0; ks < 2; ++ks) {
            half8 f;
#pragma unroll
            for (int j = 0; j < 8; ++j) {
                const float v = k1[(ks * 32 + quad * 8 + j) * G3_ + gcol];
                f[j] = valid ? (_Float16)v : (_Float16)0.f;
            }
            fk1[ks] = f;
        }
#pragma unroll
        for (int ks = 0; ks < 8; ++ks) {
            half8 f;
#pragma unroll
            for (int j = 0; j < 8; ++j) {
                const float v = rk1[(ks * 32 + quad * 8 + j) * G3_ + gcol];
                f[j] = valid ? (_Float16)v : (_Float16)0.f;
            }
            frk1[ks] = f;
        }
        const int gc = w * 16 + jl;
        const float bxz = b1[gc],       bxr = b1[H_ + gc],       bxh = b1[2 * H_ + gc];
        const float bhz = b1[G3_ + gc], bhr = b1[G3_ + H_ + gc], bhh = b1[G3_ + 2 * H_ + gc];
        float h1m = 0.f;

        // staging map: thread -> (batch bb, source WG w2), 32B slice
        const int w2 = tid & 15;
        const unsigned* f1p = flags + w2 * 16;          // h1flag[w2]
        const unsigned* f2p = flags + (16 + w2) * 16;   // h2flag[w2] (back-pressure)

        for (int i = 0; i < T_; ++i) {
            // xproj prefetch + MFMA (no cross-WG dep)
            f32x4 c0 = {0.f, 0.f, 0.f, 0.f};
            {
                half8 ax0 = *(const half8*)(xn + ((size_t)i * B_ + m) * F_ + quad * 8);
                half8 ax1 = *(const half8*)(xn + ((size_t)i * B_ + m) * F_ + 32 + quad * 8);
                c0 = __builtin_amdgcn_mfma_f32_16x16x32_f16(ax0, fk1[0], c0, 0, 0, 0);
                c0 = __builtin_amdgcn_mfma_f32_16x16x32_f16(ax1, fk1[1], c0, 0, 0, 0);
            }
            // poll own source line + back-pressure, then stage 32B of h1[i-1]
            {
                const unsigned tgt1 = (unsigned)i;
                const unsigned tgt2 = (i >= 4) ? (unsigned)(i - 3) : 0u;
                while (LD_A(f1p) < tgt1 || LD_A(f2p) < tgt2)
                    __builtin_amdgcn_s_sleep(1);
                const _Float16* sp = p1 + ((unsigned)(i + 3) & 3u) * PACK_ELEMS
                                        + bb * H_ + w2 * 16;
                u64 q0 = LD_A((const u64*)sp), q1 = LD_A((const u64*)sp + 1);
                u64 q2 = LD_A((const u64*)sp + 2), q3 = LD_A((const u64*)sp + 3);
                union { u64 q[2]; u32x4 v; } a, b;
                a.q[0] = q0; a.q[1] = q1; b.q[0] = q2; b.q[1] = q3;
                *(u32x4*)(&h1s[bb][w2 * 16])     = a.v;
                *(u32x4*)(&h1s[bb][w2 * 16 + 8]) = b.v;
            }
            __syncthreads();

            f32x4 c1 = {0.f, 0.f, 0.f, 0.f};
#pragma unroll
            for (int ks = 0; ks < 8; ++ks) {
                half8 a1 = *(const half8*)(&h1s[m][ks * 32 + quad * 8]);
                c1 = __builtin_amdgcn_mfma_f32_16x16x32_f16(a1, frk1[ks], c1, 0, 0, 0);
            }
            if (valid) {
                const int r0 = mt * 16 + quad * 4;
#pragma unroll
                for (int rr = 0; rr < 4; ++rr) {
                    Cs[0][r0 + rr][lc] = c0[rr];
                    Cs[1][r0 + rr][lc] = c1[rr];
                }
            }
            __syncthreads();

            // gates + publish h1[i]
            {
                const float xz = Cs[0][bb][jl]      + bxz;
                const float xr = Cs[0][bb][16 + jl] + bxr;
                const float xh = Cs[0][bb][32 + jl] + bxh;
                const float rz = Cs[1][bb][jl]      + bhz;
                const float rr = Cs[1][bb][16 + jl] + bhr;
                const float rh = Cs[1][bb][32 + jl] + bhh;
                const float z  = sigf(xz + rz);
                const float r  = sigf(xr + rr);
                const float hh = tanhfast(xh + r * rh);
                h1m = z * h1m + (1.f - z) * hh;
                const u64 v1 = gather4(f16b(h1m), jl);
                if ((jl & 3) == 0)
                    ST_A((u64*)(p1 + (unsigned)(i & 3) * PACK_ELEMS + bb * H_ + w * 16 + jl), v1);
                asm volatile("s_waitcnt vmcnt(0)" ::: "memory");
            }
            __syncthreads();
            if (tid == 0) ST_A(&flags[w * 16], (unsigned)(i + 1));
        }
    } else {
        // ================= L2 pipeline =================
        const int w    = blockIdx.x - NWG1;
        const int gcol = valid ? (gate * H_ + w * 16 + hidx) : 0;
        half8 fk2[8], frk2[8];
#pragma unroll
        for (int ks = 0; ks < 8; ++ks) {
            half8 f2, f3;
#pragma unroll
            for (int j = 0; j < 8; ++j) {
                const int k = ks * 32 + quad * 8 + j;
                const float v2 = k2 [k * G3_ + gcol];
                const float v3 = rk2[k * G3_ + gcol];
                f2[j] = valid ? (_Float16)v2 : (_Float16)0.f;
                f3[j] = valid ? (_Float16)v3 : (_Float16)0.f;
            }
            fk2[ks] = f2; frk2[ks] = f3;
        }
        const int gc = w * 16 + jl;
        const float bxz = b2[gc],       bxr = b2[H_ + gc],       bxh = b2[2 * H_ + gc];
        const float bhz = b2[G3_ + gc], bhr = b2[G3_ + H_ + gc], bhh = b2[G3_ + 2 * H_ + gc];
        float h2m = 0.f;

        // staging map: tid<256 -> h1[t] 64B, tid>=256 -> h2[t-1] 64B
        const int halfg = tid >> 8;
        const int bbs   = (tid & 255) >> 3;
        const int seg   = tid & 7;                   // cols seg*32..+32 (src WGs 2seg, 2seg+1)
        const unsigned* fpa = flags + (halfg * 16 + 2 * seg) * 16;
        const unsigned* fpb = flags + (halfg * 16 + 2 * seg + 1) * 16;

        for (int t = 0; t < T_; ++t) {
            // poll sources, then stage both operand packs
            {
                const unsigned tgt = halfg ? (unsigned)t : (unsigned)(t + 1);
                while (LD_A(fpa) < tgt || LD_A(fpb) < tgt)
                    __builtin_amdgcn_s_sleep(1);
                const _Float16* sp = halfg
                    ? p2 + (unsigned)((t + 1) & 1) * PACK_ELEMS + bbs * H_ + seg * 32
                    : p1 + (unsigned)(t & 3) * PACK_ELEMS + bbs * H_ + seg * 32;
                u64 q[8];
#pragma unroll
                for (int k = 0; k < 8; ++k) q[k] = LD_A((const u64*)sp + k);
                _Float16* dp = halfg ? &h2s[bbs][seg * 32] : &h1s[bbs][seg * 32];
#pragma unroll
                for (int k = 0; k < 4; ++k) {
                    union { u64 q2[2]; u32x4 v; } u;
                    u.q2[0] = q[2 * k]; u.q2[1] = q[2 * k + 1];
                    *(u32x4*)(dp + k * 8) = u.v;
                }
            }
            __syncthreads();

            f32x4 c2 = {0.f, 0.f, 0.f, 0.f};
            f32x4 c3 = c2;
#pragma unroll
            for (int ks = 0; ks < 8; ++ks) {
                half8 a1 = *(const half8*)(&h1s[m][ks * 32 + quad * 8]);
                half8 a2 = *(const half8*)(&h2s[m][ks * 32 + quad * 8]);
                c2 = __builtin_amdgcn_mfma_f32_16x16x32_f16(a1, fk2[ks],  c2, 0, 0, 0);
                c3 = __builtin_amdgcn_mfma_f32_16x16x32_f16(a2, frk2[ks], c3, 0, 0, 0);
            }
            if (valid) {
                const int r0 = mt * 16 + quad * 4;
#pragma unroll
                for (int rr = 0; rr < 4; ++rr) {
                    Cs[0][r0 + rr][lc] = c2[rr];
                    Cs[1][r0 + rr][lc] = c3[rr];
                }
            }
            __syncthreads();

            // gates + publish h2[t]
            {
                const float xz = Cs[0][bb][jl]      + bxz;
                const float xr = Cs[0][bb][16 + jl] + bxr;
                const float xh = Cs[0][bb][32 + jl] + bxh;
                const float rz = Cs[1][bb][jl]      + bhz;
                const float rr = Cs[1][bb][16 + jl] + bhr;
                const float rh = Cs[1][bb][32 + jl] + bhh;
                const float z  = sigf(xz + rz);
                const float r  = sigf(xr + rr);
                const float hh = tanhfast(xh + r * rh);
                h2m = z * h2m + (1.f - z) * hh;
                const u64 v2 = gather4(f16b(h2m), jl);
                if ((jl & 3) == 0)
                    ST_A((u64*)(p2 + (unsigned)(t & 1) * PACK_ELEMS + bb * H_ + w * 16 + jl), v2);
                asm volatile("s_waitcnt vmcnt(0)" ::: "memory");
            }
            __syncthreads();
            if (tid == 0) ST_A(&flags[(16 + w) * 16], (unsigned)(t + 1));
        }

        // ---- final dense: out[b][o] += sum_j h2[b][16w+j] * wd[16w+j][o]
        hs[bb][jl] = h2m;                // h2m = h2[T-1]
        __syncthreads();
        const int o  = tid & 63;
        const int bq = tid >> 6;         // 0..7
        for (int pass = 0; pass < 4; ++pass) {
            const int b = pass * 8 + bq;
            float acc = 0.f;
#pragma unroll
            for (int j = 0; j < 16; ++j) acc += hs[b][j] * wd[(w * 16 + j) * OUT_ + o];
            atomicAdd(&out[b * OUT_ + o], acc);
        }
    }
}

// ---------------------------------------------------------------------------
extern "C" void kernel_launch(void* const* d_in, const int* in_sizes, int n_in,
                              void* d_out, int out_size, void* d_ws, size_t ws_size,
                              hipStream_t stream) {
    const float* x     = (const float*)d_in[0];
    const float* gamma = (const float*)d_in[1];
    const float* beta  = (const float*)d_in[2];
    const float* k1    = (const float*)d_in[3];
    const float* rk1   = (const float*)d_in[4];
    const float* b1    = (const float*)d_in[5];
    const float* k2    = (const float*)d_in[6];
    const float* rk2   = (const float*)d_in[7];
    const float* b2    = (const float*)d_in[8];
    const float* wd    = (const float*)d_in[9];
    const float* bd    = (const float*)d_in[10];
    float* out = (float*)d_out;

    char* ws = (char*)d_ws;
    _Float16*     xn    = (_Float16*)ws;
    _Float16*     p1    = (_Float16*)(ws + P1_OFF);
    _Float16*     p2    = (_Float16*)(ws + P2_OFF);
    unsigned int* flags = (unsigned int*)(ws + FLAG_OFF);

    hipLaunchKernelGGL(init_kernel, dim3(16), dim3(256), 0, stream, out, bd, p1, flags);
    hipLaunchKernelGGL(ln_kernel, dim3(B_ * T_ / 16), dim3(256), 0, stream, x, gamma, beta, xn);

    void* args[] = {(void*)&xn, (void*)&k1, (void*)&rk1, (void*)&b1, (void*)&k2,
                    (void*)&rk2, (void*)&b2, (void*)&wd, (void*)&out,
                    (void*)&p1, (void*)&p2, (void*)&flags};
    hipLaunchCooperativeKernel((void*)gru_main, dim3(TOTAL_WG), dim3(WGT), args, 0, stream);
}